// Round 10
// baseline (216.841 us; speedup 1.0000x reference)
//
#include <hip/hip_runtime.h>
#include <hip/hip_bf16.h>
#include <hip/hip_cooperative_groups.h>
#include <cstdint>

namespace cg = cooperative_groups;

#define T_TOK 4096
#define D_DIM 1024
#define E_EXP 8
#define CAP   640          // int(1.25 * 4096 / 8)
#define MAXDROP 3456
#define MT    10           // 64-row m-tiles per expert (xg granularity)

typedef __attribute__((ext_vector_type(8))) short short8;
typedef __attribute__((ext_vector_type(4))) float f32x4;

// round-to-nearest-even float -> bf16 bits
__device__ inline unsigned short f2bf(float f) {
    uint32_t u = __float_as_uint(f);
    u += 0x7fffu + ((u >> 16) & 1u);
    return (unsigned short)(u >> 16);
}

// async global->LDS DMA: per-lane global address (this lane's 16-B slice),
// wave-uniform LDS base; HW writes at ldsbase + lane*16.
__device__ inline void dma16(const void* g, void* l) {
    __builtin_amdgcn_global_load_lds(
        (const __attribute__((address_space(1))) unsigned int*)g,
        (__attribute__((address_space(3))) unsigned int*)l, 16, 0, 0);
}

// tiled bf16 images: per 64x64 tile, 8 planes g, each [64 rows][8 shorts] = 1 KB
#define WB_TILE(e, nt, kt) ((((size_t)(e) * 16 + (nt)) * 16 + (kt)) * 4096)
#define XG_TILE(e, mt, kt) ((((size_t)(e) * MT + (mt)) * 16 + (kt)) * 4096)

// ---------------- fused front-end: trans + gate | sync | scan+aux | sync | gather ----
// cooperative, 256 blocks x 1024 threads (1 block/CU)
__global__ __launch_bounds__(1024) void fused_front(
    const float* __restrict__ x, const float* __restrict__ Wg,
    const float* __restrict__ bg, const float* __restrict__ W,
    unsigned short* __restrict__ Wb, unsigned short* __restrict__ xg,
    int* __restrict__ top_idx, float* __restrict__ top_prob,
    int* __restrict__ tok_list, int* __restrict__ cnt,
    float* __restrict__ ppart,            // [4096][8] per-token probs
    float* __restrict__ out, float* __restrict__ out_aux)
{
    __shared__ union {
        unsigned short tile4[4][64][66];  // 33,792 B (trans phase, 4 tiles)
        float WgT[8][1024];               // 32,768 B (gate phase)
        struct {
            int counts[64][8];
            int excl[64][8];
            int fulltot[8];
            float pred[16][8];
            int droplist[MAXDROP];
            int ndrop;
        } sc;                             // ~18.5 KB (scan phase)
    } u;

    cg::grid_group grid = cg::this_grid();
    int bid  = blockIdx.x;
    int tid  = threadIdx.x;
    int wv   = tid >> 6;
    int lane = tid & 63;
    int ltid = tid & 255;                 // 256-thread sub-block id
    int sub  = tid >> 8;                  // 0..3

    // ======== Part A: W[e][k][n] fp32 -> Wb tiled bf16 (8 tiles per block) ========
    #pragma unroll 1
    for (int it = 0; it < 2; it++) {
        int tile_id = bid * 8 + it * 4 + sub;     // 0..2047
        int e  = tile_id >> 8;
        int kt = (tile_id >> 4) & 15;
        int nt = tile_id & 15;
        int k0 = kt * 64, n0 = nt * 64;
        const float* Wsrc = W + (size_t)e * D_DIM * D_DIM;
        #pragma unroll
        for (int p = 0; p < 4; p++) {
            int kk = p * 16 + (ltid >> 4);
            int nn = (ltid & 15) * 4;
            float4 v = *(const float4*)(Wsrc + (size_t)(k0 + kk) * D_DIM + n0 + nn);
            ushort4 uq;
            uq.x = f2bf(v.x); uq.y = f2bf(v.y); uq.z = f2bf(v.z); uq.w = f2bf(v.w);
            *(ushort4*)&u.tile4[sub][kk][nn] = uq;
        }
        __syncthreads();
        unsigned short* dst = Wb + WB_TILE(e, nt, kt);
        #pragma unroll
        for (int p = 0; p < 2; p++) {
            int c = ltid + 256 * p;       // chunk = g*64 + n
            int g = c >> 6, n = c & 63;
            short8 v;
            #pragma unroll
            for (int z = 0; z < 8; z++) v[z] = (short)u.tile4[sub][g * 8 + z][n];
            *(short8*)&dst[(size_t)c * 8] = v;   // coalesced
        }
        __syncthreads();
    }

    // ======== Part B: gating, 16 tokens/block, Wg transposed in LDS ========
    {
        const float4* wr = (const float4*)(Wg + (size_t)tid * 8);
        float4 a = wr[0], bq = wr[1];
        u.WgT[0][tid] = a.x;  u.WgT[1][tid] = a.y;  u.WgT[2][tid] = a.z;  u.WgT[3][tid] = a.w;
        u.WgT[4][tid] = bq.x; u.WgT[5][tid] = bq.y; u.WgT[6][tid] = bq.z; u.WgT[7][tid] = bq.w;
    }
    __syncthreads();
    {
        int t = bid * 16 + wv;
        const float* xr = x + (size_t)t * D_DIM;
        float acc[8];
        #pragma unroll
        for (int e = 0; e < 8; e++) acc[e] = 0.f;
        #pragma unroll
        for (int ii = 0; ii < 8; ii++) {
            int da = lane + 128 * ii;
            int db = da + 64;
            float xa = xr[da];
            float xc = xr[db];
            #pragma unroll
            for (int e = 0; e < 8; e++)
                acc[e] += xa * u.WgT[e][da] + xc * u.WgT[e][db];
        }
        #pragma unroll
        for (int off = 32; off > 0; off >>= 1) {
            #pragma unroll
            for (int e = 0; e < 8; e++) acc[e] += __shfl_xor(acc[e], off, 64);
        }
        if (lane == 0) {
            float lg[8];
            #pragma unroll
            for (int e = 0; e < 8; e++) lg[e] = acc[e] + bg[e];
            float m = lg[0]; int am = 0;
            #pragma unroll
            for (int e = 1; e < 8; e++) { if (lg[e] > m) { m = lg[e]; am = e; } }
            float ex[8], s = 0.f;
            #pragma unroll
            for (int e = 0; e < 8; e++) { ex[e] = expf(lg[e] - m); s += ex[e]; }
            float inv = 1.f / s;
            top_idx[t]  = am;
            top_prob[t] = ex[am] * inv;
            float* pp = ppart + (size_t)t * 8;    // plain stores, no atomics/zeroing
            #pragma unroll
            for (int e = 0; e < 8; e++) pp[e] = ex[e] * inv;
        }
    }

    grid.sync();

    // ======== Part C: scan + aux (block 0 only) ========
    if (bid == 0) {
        unsigned long long ltmask = (lane == 0) ? 0ull : ((~0ull) >> (64 - lane));
        if (tid == 0) u.sc.ndrop = 0;

        int ecache[4];
        #pragma unroll
        for (int c = 0; c < 4; c++)
            ecache[c] = top_idx[(4 * wv + c) * 64 + lane];

        #pragma unroll
        for (int c = 0; c < 4; c++) {
            int chunk = 4 * wv + c;
            int e = ecache[c];
            #pragma unroll
            for (int q = 0; q < 8; q++) {
                unsigned long long mk = __ballot(e == q);
                int tot = __popcll(mk);
                if (lane == q) u.sc.counts[chunk][q] = tot;
            }
        }
        __syncthreads();

        if (wv == 0) {
            #pragma unroll
            for (int q = 0; q < 8; q++) {
                int v = u.sc.counts[lane][q];
                int orig = v;
                #pragma unroll
                for (int off = 1; off < 64; off <<= 1) {
                    int n = __shfl_up(v, off, 64);
                    if (lane >= off) v += n;
                }
                u.sc.excl[lane][q] = v - orig;
                int total = __shfl(v, 63, 64);
                if (lane == 0) {
                    u.sc.fulltot[q] = total;
                    cnt[q] = total < CAP ? total : CAP;
                }
            }
        }
        __syncthreads();

        #pragma unroll
        for (int c = 0; c < 4; c++) {
            int chunk = 4 * wv + c;
            int t = chunk * 64 + lane;
            int e = ecache[c];
            int pos = 0;
            #pragma unroll
            for (int q = 0; q < 8; q++) {
                unsigned long long mk = __ballot(e == q);
                if (e == q) pos = u.sc.excl[chunk][q] + __popcll(mk & ltmask);
            }
            if (pos < CAP) {
                tok_list[e * CAP + pos] = t;
            } else {
                int di = atomicAdd(&u.sc.ndrop, 1);
                u.sc.droplist[di] = t;
            }
        }
        __syncthreads();

        // zero dropped rows of out (usually none)
        int nd = u.sc.ndrop;
        int grp = tid >> 8;
        int col = (tid & 255) * 4;
        float4 z = {0.f, 0.f, 0.f, 0.f};
        for (int d = grp; d < nd; d += 4) {
            int row = u.sc.droplist[d];
            *(float4*)&out[(size_t)row * D_DIM + col] = z;
        }

        // aux: E * sum_e (fulltot_e/T) * (sum_t probs_te / T), reduce ppart[4096][8]
        float p[8];
        #pragma unroll
        for (int e = 0; e < 8; e++) p[e] = 0.f;
        #pragma unroll
        for (int i = 0; i < 4; i++) {
            const float* pr = ppart + ((size_t)(tid * 4 + i)) * 8;
            #pragma unroll
            for (int e = 0; e < 8; e++) p[e] += pr[e];
        }
        #pragma unroll
        for (int off = 32; off > 0; off >>= 1) {
            #pragma unroll
            for (int e = 0; e < 8; e++) p[e] += __shfl_xor(p[e], off, 64);
        }
        if (lane == 0) {
            #pragma unroll
            for (int e = 0; e < 8; e++) u.sc.pred[wv][e] = p[e];
        }
        __syncthreads();
        if (tid == 0) {
            float s = 0.f;
            #pragma unroll
            for (int e = 0; e < 8; e++) {
                float pe = 0.f;
                #pragma unroll
                for (int w16 = 0; w16 < 16; w16++) pe += u.sc.pred[w16][e];
                s += ((float)u.sc.fulltot[e] / (float)T_TOK) * (pe / (float)T_TOK);
            }
            out_aux[0] = (float)E_EXP * s;
        }
    }

    grid.sync();

    // ======== Part D: gather x -> xg tiled bf16, 4 sub-units/block ========
    {
        int unit = bid * 4 + sub;          // 0..1023; 320 real units
        if (unit < 320) {
            int e   = unit / 40;
            int rem = unit % 40;
            int mt  = rem >> 2, ktg = rem & 3;
            int count = cnt[e];
            int m0 = mt * 64;
            if (m0 < count) {
                const int* tl = tok_list + e * CAP;
                #pragma unroll
                for (int kk = 0; kk < 4; kk++) {
                    int kt = ktg * 4 + kk;
                    unsigned short* dst = xg + XG_TILE(e, mt, kt);
                    #pragma unroll
                    for (int p = 0; p < 2; p++) {
                        int c = ltid + 256 * p;     // chunk = g*64 + row
                        int g = c >> 6, row = c & 63;
                        int gm = m0 + row;
                        int tok = tl[gm < count ? gm : count - 1];
                        const float* src = x + (size_t)tok * D_DIM + kt * 64 + g * 8;
                        float4 v0 = *(const float4*)(src);
                        float4 v1 = *(const float4*)(src + 4);
                        short8 v;
                        v[0] = f2bf(v0.x); v[1] = f2bf(v0.y); v[2] = f2bf(v0.z); v[3] = f2bf(v0.w);
                        v[4] = f2bf(v1.x); v[5] = f2bf(v1.y); v[6] = f2bf(v1.z); v[7] = f2bf(v1.w);
                        *(short8*)&dst[(size_t)c * 8] = v;   // coalesced
                    }
                }
            }
        }
    }
}

// ---------------- expert GEMM: 128x128x64 tiles, coalesced DMA, dbuf LDS ----------------
// 320 blocks (8e x 5mtt x 8ntt), 64 KB LDS -> 2 blocks/CU, all resident.
__global__ __launch_bounds__(256) void expert_gemm(
    const unsigned short* __restrict__ xg, const unsigned short* __restrict__ Wb,
    const float* __restrict__ bias,
    const int* __restrict__ tok_list, const int* __restrict__ cnt,
    const float* __restrict__ top_prob, float* __restrict__ out)
{
    int bid = blockIdx.x;
    int e   = bid / 40;
    int rem = bid % 40;
    int mtt = rem >> 3, ntt = rem & 7;
    int count = cnt[e];
    int m0 = mtt * 128;
    if (m0 >= count) return;
    int n0 = ntt * 128;

    __shared__ unsigned short Ab[2][16][64][8];   // 32 KB
    __shared__ unsigned short Bb[2][16][64][8];   // 32 KB

    int tid  = threadIdx.x;
    int lane = tid & 63, w = tid >> 6;
    int quad = lane >> 4, l16 = lane & 15;
    int mh = w >> 1;
    int nh = w & 1;
    size_t lo = (size_t)lane * 8;

    const int* tl = tok_list + e * CAP;
    const unsigned short* A0 = xg + XG_TILE(e, mtt * 2, 0) + lo;
    const unsigned short* A1 = xg + XG_TILE(e, mtt * 2 + 1, 0) + lo;
    const unsigned short* B0 = Wb + WB_TILE(e, ntt * 2, 0) + lo;
    const unsigned short* B1 = Wb + WB_TILE(e, ntt * 2 + 1, 0) + lo;

    f32x4 acc[4][4];
    #pragma unroll
    for (int i = 0; i < 4; i++)
        #pragma unroll
        for (int j = 0; j < 4; j++)
            acc[i][j] = (f32x4){0.f, 0.f, 0.f, 0.f};

    auto stage = [&](int kt, int buf) {
        const unsigned short* a0 = A0 + (size_t)kt * 4096;
        const unsigned short* a1 = A1 + (size_t)kt * 4096;
        const unsigned short* b0 = B0 + (size_t)kt * 4096;
        const unsigned short* b1 = B1 + (size_t)kt * 4096;
        #pragma unroll
        for (int d = 0; d < 8; d++) {
            int g = w + 4 * d;
            if (g < 8)        dma16(a0 + (size_t)g * 512,        &Ab[buf][g][0][0]);
            else if (g < 16)  dma16(a1 + (size_t)(g - 8) * 512,  &Ab[buf][g][0][0]);
            else if (g < 24)  dma16(b0 + (size_t)(g - 16) * 512, &Bb[buf][g - 16][0][0]);
            else              dma16(b1 + (size_t)(g - 24) * 512, &Bb[buf][g - 16][0][0]);
        }
    };

    stage(0, 0);
    int cur = 0;
    #pragma unroll 1
    for (int kt = 0; kt < 16; kt++) {
        __syncthreads();
        if (kt + 1 < 16) stage(kt + 1, cur ^ 1);

        #pragma unroll
        for (int s = 0; s < 2; s++) {
            int g = s * 4 + quad;
            short8 af[4], bf[4];
            #pragma unroll
            for (int i = 0; i < 4; i++)
                af[i] = *(const short8*)&Ab[cur][mh * 8 + g][16 * i + l16][0];
            #pragma unroll
            for (int j = 0; j < 4; j++)
                bf[j] = *(const short8*)&Bb[cur][nh * 8 + g][16 * j + l16][0];
            #pragma unroll
            for (int i = 0; i < 4; i++)
                #pragma unroll
                for (int j = 0; j < 4; j++)
                    acc[i][j] = __builtin_amdgcn_mfma_f32_16x16x32_bf16(
                        af[i], bf[j], acc[i][j], 0, 0, 0);
        }
        cur ^= 1;
    }

    float bv[4];
    #pragma unroll
    for (int j = 0; j < 4; j++)
        bv[j] = bias[e * D_DIM + n0 + nh * 64 + 16 * j + l16];

    #pragma unroll
    for (int i = 0; i < 4; i++) {
        int rb = m0 + mh * 64 + 16 * i + quad * 4;
        #pragma unroll
        for (int r = 0; r < 4; r++) {
            int gm = rb + r;
            if (gm >= count) continue;
            int tok = tl[gm];
            float p = top_prob[tok];
            float* orow = out + (size_t)tok * D_DIM + n0 + nh * 64 + l16;
            #pragma unroll
            for (int j = 0; j < 4; j++)
                orow[16 * j] = (acc[i][j][r] + bv[j]) * p;
        }
    }
}

extern "C" void kernel_launch(void* const* d_in, const int* in_sizes, int n_in,
                              void* d_out, int out_size, void* d_ws, size_t ws_size,
                              hipStream_t stream) {
    const float* x  = (const float*)d_in[0];   // [4096,1024]
    const float* Wg = (const float*)d_in[1];   // [1024,8]
    const float* bg = (const float*)d_in[2];   // [8]
    const float* W  = (const float*)d_in[3];   // [8,1024,1024]
    const float* b  = (const float*)d_in[4];   // [8,1024]
    float* out = (float*)d_out;                // [4096*1024 + 1]

    char* ws = (char*)d_ws;                    // ~27.5 MB used
    unsigned short* Wb = (unsigned short*)(ws + 0);          // 16,777,216 B (tiled)
    unsigned short* xg = (unsigned short*)(ws + 16777216);   // 10,485,760 B (tiled)
    int*   top_idx  = (int*)(ws + 27262976);   // 16384 B
    float* top_prob = (float*)(ws + 27279360); // 16384 B
    int*   tok_list = (int*)(ws + 27295744);   // 20480 B
    int*   cnt      = (int*)(ws + 27316224);   // 32 B
    float* ppart    = (float*)(ws + 27316256); // 131072 B ([4096][8])
    float* out_aux  = out + (size_t)T_TOK * D_DIM;

    void* args[] = {
        (void*)&x, (void*)&Wg, (void*)&bg, (void*)&W,
        (void*)&Wb, (void*)&xg, (void*)&top_idx, (void*)&top_prob,
        (void*)&tok_list, (void*)&cnt, (void*)&ppart,
        (void*)&out, (void*)&out_aux
    };
    hipLaunchCooperativeKernel((void*)fused_front, dim3(256), dim3(1024),
                               args, 0, stream);
    hipLaunchKernelGGL(expert_gemm, dim3(E_EXP * 5 * 8), dim3(256), 0, stream,
                       xg, Wb, b, tok_list, cnt, top_prob, out);
}